// Round 8
// baseline (220.815 us; speedup 1.0000x reference)
//
#include <hip/hip_runtime.h>
#include <hip/hip_bf16.h>

// ParamTable: idx = base-2 encoding of 16-wide x_pa row (MSB first),
// p = params[idx] (65536 x 2 f32), outputs concatenated:
// out[0..B) = col0, out[B..2B) = col1.
//
// Structure (R7, verified absmax=0): lane-contiguous 16B loads (wave = 1KiB
// = 16 rows, 16 line-transactions/inst), index assembled across each 4-lane
// quad via two quad-local __shfl_xor; quad-duplicated gathers/stores
// coalesce to the same line.
//
// *** DIAGNOSTIC ROUND: PASSES=3 (idempotent) so the dispatch (~100us)
// clears the top-5 cutoff (~79us harness fills) and we get counters for
// THIS structure. T_kernel ~= dur/3. REVERT to PASSES=1 next round.
// Decision rule: per-pass <=28us -> roofline; >=33us -> transpose rewrite.

typedef int v4i __attribute__((ext_vector_type(4)));

constexpr int BLOCK = 256;           // 4 waves
constexpr int ROWS_PER_BLOCK = 256;  // 64 rows per wave (4 rounds x 16 rows)
constexpr int PASSES = 3;            // DIAGNOSTIC; set to 1 to ship

__global__ __launch_bounds__(BLOCK) void paramtable_gather_kernel(
    const int* __restrict__ x_pa,      // [B,16] values in {0,1}
    const float* __restrict__ params,  // [65536, 2]
    float* __restrict__ out,           // [2*B]
    int B) {
    const int lane = threadIdx.x & 63;
    const int wave = threadIdx.x >> 6;                       // 0..3
    const int rowBase = blockIdx.x * ROWS_PER_BLOCK + wave * 64;
    if (rowBase >= B) return;                                // uniform

    const int m = lane >> 2;                                 // quad id: row within 16-row group
    const int shift = 12 - ((lane & 3) << 2);                // quarter q -> bit position

    // This wave's 64 rows start at 16B-chunk index rowBase*4.
    const v4i* chunks = reinterpret_cast<const v4i*>(x_pa) + (size_t)rowBase * 4;

#pragma unroll 1
    for (int pass = 0; pass < PASSES; ++pass) {
        unsigned idx[4];
#pragma unroll
        for (int k = 0; k < 4; ++k) {
            // lane-contiguous: round k covers chunks [k*64, k*64+64) = rows k*16..k*16+15
            v4i c = __builtin_nontemporal_load(chunks + k * 64 + lane);
            unsigned n = ((unsigned)c.x << 3) | ((unsigned)c.y << 2) |
                         ((unsigned)c.z << 1) |  (unsigned)c.w;
            unsigned partial = n << shift;
            // OR-reduce across the 4-lane quad (xor 1, xor 2 -> DPP quad_perm)
            unsigned p1 = partial | __shfl_xor(partial, 1);
            idx[k] = p1 | __shfl_xor(p1, 2);
        }

        // 4 independent table gathers in flight (quad-duplicated -> same line).
        float2 p[4];
#pragma unroll
        for (int k = 0; k < 4; ++k) {
            p[k] = reinterpret_cast<const float2*>(params)[idx[k]];
        }

        // Stores: 16 distinct dwords per instruction (quad-duplicated,
        // idempotent, one 64B line per instruction).
#pragma unroll
        for (int k = 0; k < 4; ++k) {
            int b = rowBase + k * 16 + m;
            __builtin_nontemporal_store(p[k].x, out + b);
            __builtin_nontemporal_store(p[k].y, out + B + b);
        }

        // Prevent cross-pass CSE so each pass re-issues full memory traffic.
        asm volatile("" ::: "memory");
    }
}

extern "C" void kernel_launch(void* const* d_in, const int* in_sizes, int n_in,
                              void* d_out, int out_size, void* d_ws, size_t ws_size,
                              hipStream_t stream) {
    // setup_inputs order: x [B] (unused), x_pa [B*16], params [65536*2]
    const int*   x_pa   = (const int*)d_in[1];
    const float* params = (const float*)d_in[2];
    float*       out    = (float*)d_out;

    int B = in_sizes[0];  // x has B elements

    int blocks = (B + ROWS_PER_BLOCK - 1) / ROWS_PER_BLOCK;
    paramtable_gather_kernel<<<blocks, BLOCK, 0, stream>>>(x_pa, params, out, B);
}

// Round 9
// 195.646 us; speedup vs baseline: 1.1286x; 1.1286x over previous
//
#include <hip/hip_runtime.h>
#include <hip/hip_bf16.h>

// ParamTable: idx = base-2 encoding of 16-wide x_pa row (MSB first),
// p = params[idx] (65536 x 2 f32), outputs concatenated:
// out[0..B) = col0, out[B..2B) = col1.
//
// R8 analysis: cold-pass ~33us vs ~25us HBM floor; warm (L3) pass ~13us ->
// issue/L3 cheap, gap = unhidden HBM latency + VMEM op count. This version
// removes all quad-duplication: after the quad OR-reduce each lane selects
// idx[lane&3] (source-side select) and owns row (lane&3)*16 + (lane>>2) --
// a bijection over the wave's 64 rows. Per 64 rows: 4 lane-contiguous 16B
// loads + ONE 64-wide float2 gather + TWO contiguous 256B stores
// (7 VMEM instrs, was 16; same line-transaction count).

typedef int v4i __attribute__((ext_vector_type(4)));

constexpr int BLOCK = 256;           // 4 waves
constexpr int ROWS_PER_BLOCK = 256;  // 64 rows per wave

__global__ __launch_bounds__(BLOCK) void paramtable_gather_kernel(
    const int* __restrict__ x_pa,      // [B,16] values in {0,1}
    const float* __restrict__ params,  // [65536, 2]
    float* __restrict__ out,           // [2*B]
    int B) {
    const int lane = threadIdx.x & 63;
    const int wave = threadIdx.x >> 6;                       // 0..3
    const int rowBase = blockIdx.x * ROWS_PER_BLOCK + wave * 64;
    if (rowBase >= B) return;                                // uniform (B % 256 == 0)

    const int shift = 12 - ((lane & 3) << 2);                // quarter -> bit position

    // Wave's 64 rows = 1 KiB x 4: lane-contiguous 16B chunks.
    const v4i* chunks = reinterpret_cast<const v4i*>(x_pa) + (size_t)rowBase * 4;

    unsigned idx[4];
#pragma unroll
    for (int k = 0; k < 4; ++k) {
        // round k covers rows k*16 .. k*16+15 (chunks k*64 .. k*64+63)
        v4i c = __builtin_nontemporal_load(chunks + k * 64 + lane);
        unsigned n = ((unsigned)c.x << 3) | ((unsigned)c.y << 2) |
                     ((unsigned)c.z << 1) |  (unsigned)c.w;
        unsigned partial = n << shift;
        // OR-reduce across the 4-lane quad (xor 1, xor 2 -> DPP quad_perm):
        // idx[k] = full 16-bit index of row k*16 + (lane>>2), in all 4 quad lanes
        unsigned p1 = partial | __shfl_xor(partial, 1);
        idx[k] = p1 | __shfl_xor(p1, 2);
    }

    // Source-side select: lane l exposes k = l&3, owning row (l&3)*16 + (l>>2).
    // Bijection over the wave's 64 rows (l = 4m+k <-> row k*16+m).
    const int k0 = lane & 3;
    unsigned my = (k0 == 0) ? idx[0] : (k0 == 1) ? idx[1] : (k0 == 2) ? idx[2] : idx[3];

    // ONE 64-wide gather (8B/lane, table stays L2-hot -> no nt hint).
    float2 p = reinterpret_cast<const float2*>(params)[my];

    // TWO contiguous 256B stores (permuted within the 64-row range -> same
    // 4 lines per store, fully coalesced).
    const int row = rowBase + (k0 << 4) + (lane >> 2);
    __builtin_nontemporal_store(p.x, out + row);
    __builtin_nontemporal_store(p.y, out + B + row);
}

extern "C" void kernel_launch(void* const* d_in, const int* in_sizes, int n_in,
                              void* d_out, int out_size, void* d_ws, size_t ws_size,
                              hipStream_t stream) {
    // setup_inputs order: x [B] (unused), x_pa [B*16], params [65536*2]
    const int*   x_pa   = (const int*)d_in[1];
    const float* params = (const float*)d_in[2];
    float*       out    = (float*)d_out;

    int B = in_sizes[0];  // x has B elements

    int blocks = (B + ROWS_PER_BLOCK - 1) / ROWS_PER_BLOCK;
    paramtable_gather_kernel<<<blocks, BLOCK, 0, stream>>>(x_pa, params, out, B);
}